// Round 7
// baseline (237.449 us; speedup 1.0000x reference)
//
#include <hip/hip_runtime.h>
#include <math.h>

#define T_STEPS 32
#define B_SZ    512
#define D_SZ    1024
#define C_SZ    1000
#define KZ      8           // GEMM2 split-K factor
#define HP      132         // LDS h-tile pitch (bf16), even; breaks bank aliasing

typedef __bf16 bf16x8 __attribute__((ext_vector_type(8)));
typedef float  f32x4  __attribute__((ext_vector_type(4)));

__device__ __forceinline__ unsigned short f2bf(float f) {
    unsigned u = __float_as_uint(f);
    unsigned r = u + 0x7FFFu + ((u >> 16) & 1u);   // RNE
    return (unsigned short)(r >> 16);
}
__device__ __forceinline__ float bf2f(unsigned short b) {
    return __uint_as_float(((unsigned)b) << 16);
}

__device__ __forceinline__ void async_copy16(const void* g, void* l) {
    __builtin_amdgcn_global_load_lds(
        (const __attribute__((address_space(1))) unsigned int*)g,
        (__attribute__((address_space(3))) unsigned int*)l,
        16, 0, 0);
}

// pack 8 fp32 -> bf16x8 (RNE; compiler may fuse to v_cvt_pk_bf16_f32)
__device__ __forceinline__ bf16x8 cvt8(const float4 u, const float4 v) {
    bf16x8 r;
    r[0] = (__bf16)u.x; r[1] = (__bf16)u.y; r[2] = (__bf16)u.z; r[3] = (__bf16)u.w;
    r[4] = (__bf16)v.x; r[5] = (__bf16)v.y; r[6] = (__bf16)v.z; r[7] = (__bf16)v.w;
    return r;
}

// ---------------- cast W1, W2 -> bf16 (x is consumed fp32 directly) ----------
#define NW14  262144   // W1: 1M floats / 4
#define NW24  256000   // W2: 1.024M floats / 4
#define NWTOT (NW14 + NW24)   // 518144 = 2024 * 256

__global__ __launch_bounds__(256) void cast_w_k(
    const float* __restrict__ W1, unsigned short* __restrict__ W1_bf,
    const float* __restrict__ W2, unsigned short* __restrict__ W2_bf)
{
    const int idx = blockIdx.x * 256 + threadIdx.x;
    const float4* s; ushort4* d; int j;
    if (idx < NW14) { s = (const float4*)W1; d = (ushort4*)W1_bf; j = idx; }
    else            { s = (const float4*)W2; d = (ushort4*)W2_bf; j = idx - NW14; }
    const float4 v = s[j];
    ushort4 o;
    o.x = f2bf(v.x); o.y = f2bf(v.y); o.z = f2bf(v.z); o.w = f2bf(v.w);
    d[j] = o;
}

// ---------------- fused GEMM1 + bias + LIF scan -> spike counts ----------------
// X fp32 [T*B, D] read directly (A-fragments global->reg->cvt, no LDS for A).
// Bm = W1_bf [D,D] staged through LDS (BK=64, XOR chunk swizzle).
// Block tile: M-rows {t*512 + b0 + bb} (rho = t*4+bb), N-tile 128.
__global__ __launch_bounds__(256) void gemm1_scan_k(
    const float* __restrict__ X, const unsigned short* __restrict__ Bm,
    const float* __restrict__ bias, unsigned short* __restrict__ cnt)
{
    __shared__ __align__(16) unsigned short smem[128 * HP];  // 33792 B
    unsigned short* Bs = smem;           // 16 KB staging (aliased by h-tile later)

    const int tid  = threadIdx.x;
    const int wave = tid >> 6;
    const int lane = tid & 63;
    const int lm   = lane & 15;
    const int quad = lane >> 4;
    const int wm   = (wave >> 1) * 64;
    const int wn   = (wave & 1) * 64;

    // XCD swizzle: the 8 blocks sharing an A-slab (same yb) share an XCD
    const int f  = blockIdx.x;
    const int yb = f & 127;
    const int xb = f >> 7;
    const int b0 = yb * 4;
    const int n0 = xb * 128;

    f32x4 acc[4][4];
    #pragma unroll
    for (int i = 0; i < 4; ++i)
        #pragma unroll
        for (int j = 0; j < 4; ++j)
            acc[i][j] = (f32x4){0.f, 0.f, 0.f, 0.f};

    // B staging geometry: slot s = p*256+tid; row = s>>3; phys q = s&7;
    // global chunk gq = q ^ (row&7)
    int srow[4], sgq[4];
    unsigned ldsoff[4];
    #pragma unroll
    for (int p = 0; p < 4; ++p) {
        const int s = p * 256 + tid;
        const int rho = s >> 3;
        srow[p] = rho;
        sgq[p]  = (s & 7) ^ (rho & 7);
        ldsoff[p] = (unsigned)(p * 256 + wave * 64) * 16u;
    }
    const int fq0 = quad ^ (lm & 7);   // phys chunk for kk=0; kk=1 is fq0^4

    // A-fragment row base pointers (4 rows per lane), + quad's k-phase
    const float* arow[4];
    #pragma unroll
    for (int i = 0; i < 4; ++i) {
        const int rho = wm + i * 16 + lm;
        arow[i] = X + (size_t)((rho >> 2) * 512 + b0 + (rho & 3)) * D_SZ + quad * 8;
    }

    for (int k0 = 0; k0 < D_SZ; k0 += 64) {
        // stage B tile
        #pragma unroll
        for (int p = 0; p < 4; ++p)
            async_copy16(Bm + (size_t)(n0 + srow[p]) * D_SZ + k0 + sgq[p] * 8,
                         (char*)Bs + ldsoff[p]);
        // A-fragment loads for kk=0 (drained by the same pre-barrier vmcnt(0))
        float4 a0[4][2];
        #pragma unroll
        for (int i = 0; i < 4; ++i) {
            a0[i][0] = *(const float4*)(arow[i] + k0);
            a0[i][1] = *(const float4*)(arow[i] + k0 + 4);
        }
        __syncthreads();

        // kk = 0
        {
            bf16x8 bfr[4], af[4];
            #pragma unroll
            for (int i = 0; i < 4; ++i)
                bfr[i] = ((const bf16x8*)Bs)[(wn + i * 16 + lm) * 8 + fq0];
            #pragma unroll
            for (int i = 0; i < 4; ++i)
                af[i] = cvt8(a0[i][0], a0[i][1]);
            // issue kk=1 A-loads now; latency hides behind kk=0 MFMA
            float4 a1[4][2];
            #pragma unroll
            for (int i = 0; i < 4; ++i) {
                a1[i][0] = *(const float4*)(arow[i] + k0 + 32);
                a1[i][1] = *(const float4*)(arow[i] + k0 + 36);
            }
            #pragma unroll
            for (int mi = 0; mi < 4; ++mi)
                #pragma unroll
                for (int ni = 0; ni < 4; ++ni)
                    acc[mi][ni] = __builtin_amdgcn_mfma_f32_16x16x32_bf16(
                        af[mi], bfr[ni], acc[mi][ni], 0, 0, 0);
            // kk = 1
            bf16x8 bfr1[4], af1[4];
            #pragma unroll
            for (int i = 0; i < 4; ++i)
                bfr1[i] = ((const bf16x8*)Bs)[(wn + i * 16 + lm) * 8 + (fq0 ^ 4)];
            #pragma unroll
            for (int i = 0; i < 4; ++i)
                af1[i] = cvt8(a1[i][0], a1[i][1]);
            #pragma unroll
            for (int mi = 0; mi < 4; ++mi)
                #pragma unroll
                for (int ni = 0; ni < 4; ++ni)
                    acc[mi][ni] = __builtin_amdgcn_mfma_f32_16x16x32_bf16(
                        af1[mi], bfr1[ni], acc[mi][ni], 0, 0, 0);
        }
        __syncthreads();
    }

    // h-tile (+bias) -> LDS. local row rho = wm+mi*16+quad*4+r, col = wn+ni*16+lm
    #pragma unroll
    for (int ni = 0; ni < 4; ++ni) {
        const int nn = wn + ni * 16 + lm;
        const float bv = bias[n0 + nn];
        #pragma unroll
        for (int mi = 0; mi < 4; ++mi) {
            const f32x4 v = acc[mi][ni];
            #pragma unroll
            for (int r = 0; r < 4; ++r)
                smem[(wm + mi * 16 + quad * 4 + r) * HP + nn] = f2bf(v[r] + bv);
        }
    }
    __syncthreads();

    // LIF scan, 2 adjacent columns per thread via packed uint reads.
    // thread -> (bb = tid>>6, col pair c2 = tid&63); h[t] at local row t*4+bb.
    {
        const unsigned* smemU = (const unsigned*)smem;
        const int bb = tid >> 6;
        const int c2 = tid & 63;
        float v0 = 0.f, cv0 = 0.f, v1 = 0.f, cv1 = 0.f;
        #pragma unroll
        for (int t = 0; t < T_STEPS; ++t) {
            const unsigned u = smemU[(t * 4 + bb) * (HP / 2) + c2];
            const float h0 = bf2f((unsigned short)(u & 0xFFFFu));
            const float h1 = bf2f((unsigned short)(u >> 16));
            v0 = 0.5f * (v0 + h0);
            const float s0 = (v0 >= 1.0f) ? 1.0f : 0.0f;
            cv0 += s0; v0 *= (1.0f - s0);
            v1 = 0.5f * (v1 + h1);
            const float s1 = (v1 >= 1.0f) ? 1.0f : 0.0f;
            cv1 += s1; v1 *= (1.0f - s1);
        }
        ushort2 o;
        o.x = f2bf(cv0); o.y = f2bf(cv1);
        *(ushort2*)&cnt[(size_t)(b0 + bb) * D_SZ + n0 + 2 * c2] = o;
    }
}

// ---------------- GEMM2 split-K: partial[z][m][n] = cnt @ W2^T (K-slice) ------
__global__ __launch_bounds__(256) void gemm2_splitk_k(
    const unsigned short* __restrict__ A, const unsigned short* __restrict__ Bm,
    float* __restrict__ partial)
{
    __shared__ __align__(16) unsigned short As[128 * 32];
    __shared__ __align__(16) unsigned short Bs[128 * 32];

    const int tid  = threadIdx.x;
    const int wave = tid >> 6;
    const int lane = tid & 63;
    const int lm   = lane & 15;
    const int quad = lane >> 4;
    const int wm   = (wave >> 1) * 64;
    const int wn   = (wave & 1) * 64;
    const int n0   = blockIdx.x * 128;
    const int m0   = blockIdx.y * 128;
    const int kz   = blockIdx.z;

    f32x4 acc[4][4];
    #pragma unroll
    for (int i = 0; i < 4; ++i)
        #pragma unroll
        for (int j = 0; j < 4; ++j)
            acc[i][j] = (f32x4){0.f, 0.f, 0.f, 0.f};

    int srow[2], sgq[2];
    unsigned ldsoff[2];
    #pragma unroll
    for (int p = 0; p < 2; ++p) {
        const int s = p * 256 + tid;
        srow[p] = s >> 2;
        sgq[p]  = (s & 3) ^ ((srow[p] >> 1) & 3);
        ldsoff[p] = (unsigned)(p * 256 + wave * 64) * 16u;
    }
    const int fq = quad ^ ((lm >> 1) & 3);

    const int kbeg = kz * (D_SZ / KZ);
    for (int k0 = kbeg; k0 < kbeg + D_SZ / KZ; k0 += 32) {
        #pragma unroll
        for (int p = 0; p < 2; ++p) {
            async_copy16(A + (size_t)(m0 + srow[p]) * D_SZ + k0 + sgq[p] * 8,
                         (char*)As + ldsoff[p]);
            int brow = n0 + srow[p];
            if (brow > C_SZ - 1) brow = C_SZ - 1;
            async_copy16(Bm + (size_t)brow * D_SZ + k0 + sgq[p] * 8,
                         (char*)Bs + ldsoff[p]);
        }
        __syncthreads();

        bf16x8 af[4], bfr[4];
        #pragma unroll
        for (int i = 0; i < 4; ++i) {
            af[i]  = ((const bf16x8*)As)[(wm + i * 16 + lm) * 4 + fq];
            bfr[i] = ((const bf16x8*)Bs)[(wn + i * 16 + lm) * 4 + fq];
        }
        #pragma unroll
        for (int mi = 0; mi < 4; ++mi)
            #pragma unroll
            for (int ni = 0; ni < 4; ++ni)
                acc[mi][ni] = __builtin_amdgcn_mfma_f32_16x16x32_bf16(
                    af[mi], bfr[ni], acc[mi][ni], 0, 0, 0);
        __syncthreads();
    }

    #pragma unroll
    for (int ni = 0; ni < 4; ++ni) {
        const int nn = n0 + wn + ni * 16 + lm;
        if (nn >= C_SZ) continue;
        #pragma unroll
        for (int mi = 0; mi < 4; ++mi) {
            const f32x4 v = acc[mi][ni];
            #pragma unroll
            for (int r = 0; r < 4; ++r) {
                const int mm = m0 + wm + mi * 16 + quad * 4 + r;
                partial[((size_t)kz * B_SZ + mm) * C_SZ + nn] = v[r];
            }
        }
    }
}

// ---------------- reduce partials + bias + log_softmax ----------------
__global__ __launch_bounds__(256) void reduce_lsm_k(
    const float* __restrict__ partial, const float* __restrict__ b2,
    float* __restrict__ out)
{
    __shared__ float red_max[4];
    __shared__ float red_sum[4];

    const int b   = blockIdx.x;
    const int tid = threadIdx.x;

    float vals[4];
    float m = -1e30f;
    #pragma unroll
    for (int k = 0; k < 4; ++k) {
        const int c = tid + k * 256;
        if (c < C_SZ) {
            float s = 0.f;
            #pragma unroll
            for (int z = 0; z < KZ; ++z)
                s += partial[((size_t)z * B_SZ + b) * C_SZ + c];
            vals[k] = s * (1.0f / (float)T_STEPS) + b2[c];
        } else {
            vals[k] = -1e30f;
        }
        m = fmaxf(m, vals[k]);
    }
    #pragma unroll
    for (int off = 32; off > 0; off >>= 1)
        m = fmaxf(m, __shfl_down(m, off, 64));
    const int wave = tid >> 6;
    const int lane = tid & 63;
    if (lane == 0) red_max[wave] = m;
    __syncthreads();
    m = fmaxf(fmaxf(red_max[0], red_max[1]), fmaxf(red_max[2], red_max[3]));

    float s = 0.f;
    #pragma unroll
    for (int k = 0; k < 4; ++k) {
        const int c = tid + k * 256;
        if (c < C_SZ) s += __expf(vals[k] - m);
    }
    #pragma unroll
    for (int off = 32; off > 0; off >>= 1)
        s += __shfl_down(s, off, 64);
    if (lane == 0) red_sum[wave] = s;
    __syncthreads();
    s = red_sum[0] + red_sum[1] + red_sum[2] + red_sum[3];

    const float lse = m + logf(s);
    #pragma unroll
    for (int k = 0; k < 4; ++k) {
        const int c = tid + k * 256;
        if (c < C_SZ) out[(size_t)b * C_SZ + c] = vals[k] - lse;
    }
}

extern "C" void kernel_launch(void* const* d_in, const int* in_sizes, int n_in,
                              void* d_out, int out_size, void* d_ws, size_t ws_size,
                              hipStream_t stream)
{
    const float* x  = (const float*)d_in[0];  // [T,B,D]
    const float* W1 = (const float*)d_in[1];  // [D,D]
    const float* b1 = (const float*)d_in[2];  // [D]
    const float* W2 = (const float*)d_in[3];  // [C,D]
    const float* b2 = (const float*)d_in[4];  // [C]
    float* out = (float*)d_out;               // [B,C]

    char* ws = (char*)d_ws;
    unsigned short* W1_bf   = (unsigned short*)(ws);              //  2,097,152 B
    unsigned short* W2_bf   = (unsigned short*)(ws + 2097152);    //  2,048,000 B
    unsigned short* cnt_bf  = (unsigned short*)(ws + 4145152);    //  1,048,576 B
    float*          partial = (float*)(ws + 5193728);             // 16,384,000 B
    // total 21,577,728 B < ws_size

    // 1) cast weights only (x consumed fp32 directly by gemm1)
    cast_w_k<<<NWTOT / 256, 256, 0, stream>>>(W1, W1_bf, W2, W2_bf);

    // 2) fused GEMM1 (A direct-from-global fp32, B via LDS) + bias + LIF scan
    gemm1_scan_k<<<(B_SZ / 4) * (D_SZ / 128), 256, 0, stream>>>(
        x, W1_bf, b1, cnt_bf);

    // 3) GEMM2 split-K exclusive partials
    {
        dim3 grid((C_SZ + 127) / 128, B_SZ / 128, KZ);
        gemm2_splitk_k<<<grid, 256, 0, stream>>>(cnt_bf, W2_bf, partial);
    }

    // 4) reduce + bias + 1/T + log_softmax
    reduce_lsm_k<<<B_SZ, 256, 0, stream>>>(partial, b2, out);
}

// Round 8
// 163.785 us; speedup vs baseline: 1.4498x; 1.4498x over previous
//
#include <hip/hip_runtime.h>
#include <math.h>

#define T_STEPS 32
#define B_SZ    512
#define D_SZ    1024
#define C_SZ    1000
#define KZ      8           // GEMM2 split-K factor
#define HP      132         // LDS h-tile pitch (bf16); breaks bank aliasing

typedef __bf16 bf16x8 __attribute__((ext_vector_type(8)));
typedef float  f32x4  __attribute__((ext_vector_type(4)));

__device__ __forceinline__ unsigned short f2bf(float f) {
    unsigned u = __float_as_uint(f);
    unsigned r = u + 0x7FFFu + ((u >> 16) & 1u);   // RNE
    return (unsigned short)(r >> 16);
}
__device__ __forceinline__ float bf2f(unsigned short b) {
    return __uint_as_float(((unsigned)b) << 16);
}

__device__ __forceinline__ void async_copy16(const void* g, void* l) {
    __builtin_amdgcn_global_load_lds(
        (const __attribute__((address_space(1))) unsigned int*)g,
        (__attribute__((address_space(3))) unsigned int*)l,
        16, 0, 0);
}

// pack 8 fp32 -> 8 bf16 (RNE via compiler cvt)
__device__ __forceinline__ bf16x8 cvt8(const float4 u, const float4 v) {
    bf16x8 r;
    r[0] = (__bf16)u.x; r[1] = (__bf16)u.y; r[2] = (__bf16)u.z; r[3] = (__bf16)u.w;
    r[4] = (__bf16)v.x; r[5] = (__bf16)v.y; r[6] = (__bf16)v.z; r[7] = (__bf16)v.w;
    return r;
}

// ---------------- cast W1, W2 -> bf16 (x cast is folded into gemm1 staging) ---
#define NW14  262144   // W1: 1M floats / 4
#define NW24  256000   // W2: 1.024M floats / 4
#define NWTOT (NW14 + NW24)   // 518144 = 2024 * 256

__global__ __launch_bounds__(256) void cast_w_k(
    const float* __restrict__ W1, unsigned short* __restrict__ W1_bf,
    const float* __restrict__ W2, unsigned short* __restrict__ W2_bf)
{
    const int idx = blockIdx.x * 256 + threadIdx.x;
    const float4* s; ushort4* d; int j;
    if (idx < NW14) { s = (const float4*)W1; d = (ushort4*)W1_bf; j = idx; }
    else            { s = (const float4*)W2; d = (ushort4*)W2_bf; j = idx - NW14; }
    const float4 v = s[j];
    ushort4 o;
    o.x = f2bf(v.x); o.y = f2bf(v.y); o.z = f2bf(v.z); o.w = f2bf(v.w);
    d[j] = o;
}

// ---------------- fused GEMM1 + bias + LIF scan -> spike counts ----------------
// X fp32 [T*B, D]: A-tile staged COALESCED (8 contig floats/thread/slot) via
// global->reg->cvt->ds_write_b128 into R6's swizzled bf16 LDS layout.
// Bm = W1_bf [D,D] staged via global_load_lds w=16. BK=64, XOR chunk swizzle.
// Block tile: M-rows {t*512 + b0 + bb} (rho = t*4+bb), N-tile 128.
__global__ __launch_bounds__(256) void gemm1_scan_k(
    const float* __restrict__ X, const unsigned short* __restrict__ Bm,
    const float* __restrict__ bias, unsigned short* __restrict__ cnt)
{
    __shared__ __align__(16) unsigned short smem[128 * HP];  // 33792 B
    unsigned short* As = smem;           // 16 KB (128 rows x 8 swizzled chunks)
    unsigned short* Bs = smem + 8192;    // 16 KB

    const int tid  = threadIdx.x;
    const int wave = tid >> 6;
    const int lane = tid & 63;
    const int lm   = lane & 15;
    const int quad = lane >> 4;
    const int wm   = (wave >> 1) * 64;
    const int wn   = (wave & 1) * 64;

    // XCD swizzle: the 8 blocks sharing an A-slab (same yb) share an XCD
    const int f  = blockIdx.x;
    const int yb = f & 127;
    const int xb = f >> 7;
    const int b0 = yb * 4;
    const int n0 = xb * 128;

    f32x4 acc[4][4];
    #pragma unroll
    for (int i = 0; i < 4; ++i)
        #pragma unroll
        for (int j = 0; j < 4; ++j)
            acc[i][j] = (f32x4){0.f, 0.f, 0.f, 0.f};

    // staging geometry: slot s = p*256+tid; row rho = s>>3; phys chunk q = s&7;
    // source chunk gq = q ^ (rho&7)  (16 B chunks = 8 bf16 = 8 fp32 from X)
    int srow[4], sgq[4];
    size_t arowoff[4];
    unsigned ldsoffB[4];
    #pragma unroll
    for (int p = 0; p < 4; ++p) {
        const int s = p * 256 + tid;
        const int rho = s >> 3;
        srow[p] = rho;
        sgq[p]  = (s & 7) ^ (rho & 7);
        arowoff[p] = (size_t)((rho >> 2) * 512 + b0 + (rho & 3)) * D_SZ;  // t*512+b
        ldsoffB[p] = (unsigned)(p * 256 + wave * 64) * 16u;  // wave-uniform (lds dma)
    }
    const int fq0 = quad ^ (lm & 7);   // fragment phys chunk kk=0; kk=1 is fq0^4

    for (int k0 = 0; k0 < D_SZ; k0 += 64) {
        // B tile: async DMA (bf16 already)
        #pragma unroll
        for (int p = 0; p < 4; ++p)
            async_copy16(Bm + (size_t)(n0 + srow[p]) * D_SZ + k0 + sgq[p] * 8,
                         (char*)Bs + ldsoffB[p]);
        // A tile: coalesced fp32 reads -> cvt -> ds_write_b128 (same layout)
        #pragma unroll
        for (int p = 0; p < 4; ++p) {
            const float* src = X + arowoff[p] + k0 + sgq[p] * 8;
            const float4 u = *(const float4*)(src);
            const float4 v = *(const float4*)(src + 4);
            ((bf16x8*)As)[p * 256 + tid] = cvt8(u, v);
        }
        __syncthreads();

        #pragma unroll
        for (int kk = 0; kk < 2; ++kk) {
            const int fqk = fq0 ^ (kk * 4);
            bf16x8 af[4], bfr[4];
            #pragma unroll
            for (int i = 0; i < 4; ++i) {
                af[i]  = ((const bf16x8*)As)[(wm + i * 16 + lm) * 8 + fqk];
                bfr[i] = ((const bf16x8*)Bs)[(wn + i * 16 + lm) * 8 + fqk];
            }
            #pragma unroll
            for (int mi = 0; mi < 4; ++mi)
                #pragma unroll
                for (int ni = 0; ni < 4; ++ni)
                    acc[mi][ni] = __builtin_amdgcn_mfma_f32_16x16x32_bf16(
                        af[mi], bfr[ni], acc[mi][ni], 0, 0, 0);
        }
        __syncthreads();
    }

    // h-tile (+bias) -> LDS. local row rho = wm+mi*16+quad*4+r, col = wn+ni*16+lm
    #pragma unroll
    for (int ni = 0; ni < 4; ++ni) {
        const int nn = wn + ni * 16 + lm;
        const float bv = bias[n0 + nn];
        #pragma unroll
        for (int mi = 0; mi < 4; ++mi) {
            const f32x4 v = acc[mi][ni];
            #pragma unroll
            for (int r = 0; r < 4; ++r)
                smem[(wm + mi * 16 + quad * 4 + r) * HP + nn] = f2bf(v[r] + bv);
        }
    }
    __syncthreads();

    // LIF scan, 2 adjacent columns per thread via packed uint reads (R7-proven).
    {
        const unsigned* smemU = (const unsigned*)smem;
        const int bb = tid >> 6;
        const int c2 = tid & 63;
        float v0 = 0.f, cv0 = 0.f, v1 = 0.f, cv1 = 0.f;
        #pragma unroll
        for (int t = 0; t < T_STEPS; ++t) {
            const unsigned u = smemU[(t * 4 + bb) * (HP / 2) + c2];
            const float h0 = bf2f((unsigned short)(u & 0xFFFFu));
            const float h1 = bf2f((unsigned short)(u >> 16));
            v0 = 0.5f * (v0 + h0);
            const float s0 = (v0 >= 1.0f) ? 1.0f : 0.0f;
            cv0 += s0; v0 *= (1.0f - s0);
            v1 = 0.5f * (v1 + h1);
            const float s1 = (v1 >= 1.0f) ? 1.0f : 0.0f;
            cv1 += s1; v1 *= (1.0f - s1);
        }
        ushort2 o;
        o.x = f2bf(cv0); o.y = f2bf(cv1);
        *(ushort2*)&cnt[(size_t)(b0 + bb) * D_SZ + n0 + 2 * c2] = o;
    }
}

// ---------------- GEMM2 split-K: partial[z][m][n] = cnt @ W2^T (K-slice) ------
__global__ __launch_bounds__(256) void gemm2_splitk_k(
    const unsigned short* __restrict__ A, const unsigned short* __restrict__ Bm,
    float* __restrict__ partial)
{
    __shared__ __align__(16) unsigned short As[128 * 32];
    __shared__ __align__(16) unsigned short Bs[128 * 32];

    const int tid  = threadIdx.x;
    const int wave = tid >> 6;
    const int lane = tid & 63;
    const int lm   = lane & 15;
    const int quad = lane >> 4;
    const int wm   = (wave >> 1) * 64;
    const int wn   = (wave & 1) * 64;
    const int n0   = blockIdx.x * 128;
    const int m0   = blockIdx.y * 128;
    const int kz   = blockIdx.z;

    f32x4 acc[4][4];
    #pragma unroll
    for (int i = 0; i < 4; ++i)
        #pragma unroll
        for (int j = 0; j < 4; ++j)
            acc[i][j] = (f32x4){0.f, 0.f, 0.f, 0.f};

    int srow[2], sgq[2];
    unsigned ldsoff[2];
    #pragma unroll
    for (int p = 0; p < 2; ++p) {
        const int s = p * 256 + tid;
        srow[p] = s >> 2;
        sgq[p]  = (s & 3) ^ ((srow[p] >> 1) & 3);
        ldsoff[p] = (unsigned)(p * 256 + wave * 64) * 16u;
    }
    const int fq = quad ^ ((lm >> 1) & 3);

    const int kbeg = kz * (D_SZ / KZ);
    for (int k0 = kbeg; k0 < kbeg + D_SZ / KZ; k0 += 32) {
        #pragma unroll
        for (int p = 0; p < 2; ++p) {
            async_copy16(A + (size_t)(m0 + srow[p]) * D_SZ + k0 + sgq[p] * 8,
                         (char*)As + ldsoff[p]);
            int brow = n0 + srow[p];
            if (brow > C_SZ - 1) brow = C_SZ - 1;
            async_copy16(Bm + (size_t)brow * D_SZ + k0 + sgq[p] * 8,
                         (char*)Bs + ldsoff[p]);
        }
        __syncthreads();

        bf16x8 af[4], bfr[4];
        #pragma unroll
        for (int i = 0; i < 4; ++i) {
            af[i]  = ((const bf16x8*)As)[(wm + i * 16 + lm) * 4 + fq];
            bfr[i] = ((const bf16x8*)Bs)[(wn + i * 16 + lm) * 4 + fq];
        }
        #pragma unroll
        for (int mi = 0; mi < 4; ++mi)
            #pragma unroll
            for (int ni = 0; ni < 4; ++ni)
                acc[mi][ni] = __builtin_amdgcn_mfma_f32_16x16x32_bf16(
                    af[mi], bfr[ni], acc[mi][ni], 0, 0, 0);
        __syncthreads();
    }

    #pragma unroll
    for (int ni = 0; ni < 4; ++ni) {
        const int nn = n0 + wn + ni * 16 + lm;
        if (nn >= C_SZ) continue;
        #pragma unroll
        for (int mi = 0; mi < 4; ++mi) {
            const f32x4 v = acc[mi][ni];
            #pragma unroll
            for (int r = 0; r < 4; ++r) {
                const int mm = m0 + wm + mi * 16 + quad * 4 + r;
                partial[((size_t)kz * B_SZ + mm) * C_SZ + nn] = v[r];
            }
        }
    }
}

// ---------------- reduce partials + bias + log_softmax ----------------
__global__ __launch_bounds__(256) void reduce_lsm_k(
    const float* __restrict__ partial, const float* __restrict__ b2,
    float* __restrict__ out)
{
    __shared__ float red_max[4];
    __shared__ float red_sum[4];

    const int b   = blockIdx.x;
    const int tid = threadIdx.x;

    float vals[4];
    float m = -1e30f;
    #pragma unroll
    for (int k = 0; k < 4; ++k) {
        const int c = tid + k * 256;
        if (c < C_SZ) {
            float s = 0.f;
            #pragma unroll
            for (int z = 0; z < KZ; ++z)
                s += partial[((size_t)z * B_SZ + b) * C_SZ + c];
            vals[k] = s * (1.0f / (float)T_STEPS) + b2[c];
        } else {
            vals[k] = -1e30f;
        }
        m = fmaxf(m, vals[k]);
    }
    #pragma unroll
    for (int off = 32; off > 0; off >>= 1)
        m = fmaxf(m, __shfl_down(m, off, 64));
    const int wave = tid >> 6;
    const int lane = tid & 63;
    if (lane == 0) red_max[wave] = m;
    __syncthreads();
    m = fmaxf(fmaxf(red_max[0], red_max[1]), fmaxf(red_max[2], red_max[3]));

    float s = 0.f;
    #pragma unroll
    for (int k = 0; k < 4; ++k) {
        const int c = tid + k * 256;
        if (c < C_SZ) s += __expf(vals[k] - m);
    }
    #pragma unroll
    for (int off = 32; off > 0; off >>= 1)
        s += __shfl_down(s, off, 64);
    if (lane == 0) red_sum[wave] = s;
    __syncthreads();
    s = red_sum[0] + red_sum[1] + red_sum[2] + red_sum[3];

    const float lse = m + logf(s);
    #pragma unroll
    for (int k = 0; k < 4; ++k) {
        const int c = tid + k * 256;
        if (c < C_SZ) out[(size_t)b * C_SZ + c] = vals[k] - lse;
    }
}

extern "C" void kernel_launch(void* const* d_in, const int* in_sizes, int n_in,
                              void* d_out, int out_size, void* d_ws, size_t ws_size,
                              hipStream_t stream)
{
    const float* x  = (const float*)d_in[0];  // [T,B,D]
    const float* W1 = (const float*)d_in[1];  // [D,D]
    const float* b1 = (const float*)d_in[2];  // [D]
    const float* W2 = (const float*)d_in[3];  // [C,D]
    const float* b2 = (const float*)d_in[4];  // [C]
    float* out = (float*)d_out;               // [B,C]

    char* ws = (char*)d_ws;
    unsigned short* W1_bf   = (unsigned short*)(ws);              //  2,097,152 B
    unsigned short* W2_bf   = (unsigned short*)(ws + 2097152);    //  2,048,000 B
    unsigned short* cnt_bf  = (unsigned short*)(ws + 4145152);    //  1,048,576 B
    float*          partial = (float*)(ws + 5193728);             // 16,384,000 B
    // total 21,577,728 B < ws_size

    // 1) cast weights only (x cast folded into gemm1 staging)
    cast_w_k<<<NWTOT / 256, 256, 0, stream>>>(W1, W1_bf, W2, W2_bf);

    // 2) fused GEMM1 (A: fp32 coalesced -> reg cvt -> LDS; B: lds-dma) + LIF scan
    gemm1_scan_k<<<(B_SZ / 4) * (D_SZ / 128), 256, 0, stream>>>(
        x, W1_bf, b1, cnt_bf);

    // 3) GEMM2 split-K exclusive partials
    {
        dim3 grid((C_SZ + 127) / 128, B_SZ / 128, KZ);
        gemm2_splitk_k<<<grid, 256, 0, stream>>>(cnt_bf, W2_bf, partial);
    }

    // 4) reduce + bias + 1/T + log_softmax
    reduce_lsm_k<<<B_SZ, 256, 0, stream>>>(partial, b2, out);
}